// Round 1
// 86.144 us; speedup vs baseline: 1.0036x; 1.0036x over previous
//
#include <hip/hip_runtime.h>

#define Bv 4
#define Vv 50000
#define Cv 160
#define TILES 782      // ceil(Vv/64)
#define WSTR 168       // LDS row stride in bf16: 336 B = 21*16 (b128-aligned, 2-way-free banks)
#define NROW 48        // Bv*12 rows of the AT table

typedef unsigned short u16;
typedef unsigned int   u32;
typedef __attribute__((ext_vector_type(8))) short bf16x8;  // 8 bf16 = 4 VGPRs
typedef __attribute__((ext_vector_type(4))) float f32x4;

__device__ __forceinline__ u16 f2bf(float f) {
    u32 u = __float_as_uint(f);
    return (u16)((u + 0x7FFFu + ((u >> 16) & 1u)) >> 16);  // RNE
}

// Single fused kernel. Per 64-vertex tile (1 block, 256 thr = 4 waves):
//   Phase B: stage W tile fp32->bf16 into LDS (coalesced float4, 40 KB HBM).
//   Phase A: redundantly build the 48x160 bf16 affine table [R|T] in LDS
//            (640 rotations/block, ~1 us aggregate, hidden under W staging).
//   GEMM:    P(64x48) = Wtile(64x160) x AT(160x48) via 15 mfma_16x16x32_bf16
//            per wave; fp32 epilogue out = M.x + T.
// No workspace, no second dispatch: removes the serialized 640-thread
// precompute launch and all d_ws usage (the 256 MiB poison fill the harness
// attaches to the workspace is the top-5 dispatch cost in rocprof).
__global__ __launch_bounds__(256) void deform_fused(
        const float* __restrict__ X,
        const float* __restrict__ Vn,
        const float* __restrict__ r6,
        const int*   __restrict__ idx,
        const float* __restrict__ W,
        float*       __restrict__ out) {
    __shared__ char smem[64 * WSTR * 2 + NROW * WSTR * 2];  // 21504 + 16128 = 37632 B
    u16*   Wl  = (u16*)smem;                     // [64][WSTR] bf16
    u16*   ATl = (u16*)(smem + 64 * WSTR * 2);   // [48][WSTR] bf16
    float* P   = (float*)smem;                   // reuses Wl region after MFMA

    const int tid = threadIdx.x;
    const int v0  = blockIdx.x * 64;

    // ---- Phase B: stage W tile (big HBM latency first). Rows of W are
    // contiguous (Cv*4 = 640 B), so the tile is one contiguous 40 KB chunk.
    for (int i = tid; i < 64 * 40; i += 256) {
        int r = i / 40, c4 = i % 40;
        int row = v0 + r;
        if (row >= Vv) row = Vv - 1;          // tail tile: dup rows, epilogue guards
        float4 q = ((const float4*)(W + (size_t)row * Cv))[c4];
        ushort4 h;
        h.x = f2bf(q.x); h.y = f2bf(q.y); h.z = f2bf(q.z); h.w = f2bf(q.w);
        *(ushort4*)&Wl[r * WSTR + c4 * 4] = h;  // 8B ds_write
    }

    // ---- Phase A: rotation-6d -> per-(b,c) affine [R | T], bf16 into LDS.
    // AT row n = b*12 + j (j: 0..8 = R row-major, 9..11 = T = c + Vn - R*c).
    // Inputs (r6/Vn/idx/X-centers, ~24 KB) are L2-warm after the first blocks.
    for (int i = tid; i < Bv * Cv; i += 256) {
        int b = i / Cv, c = i % Cv;

        const float* d6 = r6 + (size_t)(b * Cv + c) * 6;
        float a1x = d6[0], a1y = d6[1], a1z = d6[2];
        float a2x = d6[3], a2y = d6[4], a2z = d6[5];

        float n1 = fmaxf(sqrtf(a1x*a1x + a1y*a1y + a1z*a1z), 1e-8f);
        float b1x = a1x / n1, b1y = a1y / n1, b1z = a1z / n1;

        float d = b1x*a2x + b1y*a2y + b1z*a2z;
        float px = a2x - d*b1x, py = a2y - d*b1y, pz = a2z - d*b1z;
        float n2 = fmaxf(sqrtf(px*px + py*py + pz*pz), 1e-8f);
        float b2x = px / n2, b2y = py / n2, b2z = pz / n2;

        float b3x = b1y*b2z - b1z*b2y;
        float b3y = b1z*b2x - b1x*b2z;
        float b3z = b1x*b2y - b1y*b2x;

        int iv = idx[c];
        const float* xc = X + ((size_t)b * Vv + iv) * 3;
        float cx = xc[0], cy = xc[1], cz = xc[2];
        const float* vn = Vn + (size_t)(b * Cv + c) * 3;
        float vx = vn[0], vy = vn[1], vz = vn[2];

        float vals[12];
        vals[0] = b1x; vals[1]  = b1y; vals[2]  = b1z;
        vals[3] = b2x; vals[4]  = b2y; vals[5]  = b2z;
        vals[6] = b3x; vals[7]  = b3y; vals[8]  = b3z;
        vals[9]  = cx + vx - (b1x*cx + b1y*cy + b1z*cz);
        vals[10] = cy + vy - (b2x*cx + b2y*cy + b2z*cz);
        vals[11] = cz + vz - (b3x*cx + b3y*cy + b3z*cz);

#pragma unroll
        for (int j = 0; j < 12; ++j)
            ATl[(b * 12 + j) * WSTR + c] = f2bf(vals[j]);  // 2-lane/bank: free
    }
    __syncthreads();

    const int lane = tid & 63;
    const int wv   = tid >> 6;     // M-tile 0..3 (rows 16wv..16wv+15)
    const int m    = lane & 15;
    const int quad = lane >> 4;

    // A-frags: A[m][k=quad*8+j], 16B-aligned ds_read_b128 (WSTR*2 = 336 = 21*16).
    bf16x8 afr[5];
#pragma unroll
    for (int kt = 0; kt < 5; ++kt)
        afr[kt] = *(const bf16x8*)&Wl[(wv * 16 + m) * WSTR + kt * 32 + quad * 8];

    // B-frags: B[k=quad*8+j][n=m] from the LDS AT table (same stride/alignment).
    bf16x8 bfr[3][5];
#pragma unroll
    for (int nt = 0; nt < 3; ++nt)
#pragma unroll
        for (int kt = 0; kt < 5; ++kt)
            bfr[nt][kt] = *(const bf16x8*)&ATl[(nt * 16 + m) * WSTR + kt * 32 + quad * 8];

    f32x4 acc[3] = {{0,0,0,0},{0,0,0,0},{0,0,0,0}};
#pragma unroll
    for (int kt = 0; kt < 5; ++kt)
#pragma unroll
        for (int nt = 0; nt < 3; ++nt)
            acc[nt] = __builtin_amdgcn_mfma_f32_16x16x32_bf16(afr[kt], bfr[nt][kt], acc[nt], 0, 0, 0);

    __syncthreads();   // all frag reads of Wl done; safe to overwrite as P

    // C/D layout: col = lane&15, row = quad*4 + reg. P[v_local][n], stride 49.
#pragma unroll
    for (int nt = 0; nt < 3; ++nt)
#pragma unroll
        for (int r = 0; r < 4; ++r)
            P[(wv * 16 + quad * 4 + r) * 49 + nt * 16 + m] = acc[nt][r];
    __syncthreads();

    // Epilogue: thread -> (b = tid>>6, v_local = tid&63), fp32 M.x + T.
    const int b  = tid >> 6;
    const int vl = tid & 63;
    const int v  = v0 + vl;
    if (v < Vv) {
        const float* p = &P[vl * 49 + b * 12];
        const float* xp = X + ((size_t)b * Vv + v) * 3;
        float x0 = xp[0], x1 = xp[1], x2 = xp[2];
        float* op = out + ((size_t)b * Vv + v) * 3;
        op[0] = p[0]*x0 + p[1]*x1 + p[2]*x2 + p[9];
        op[1] = p[3]*x0 + p[4]*x1 + p[5]*x2 + p[10];
        op[2] = p[6]*x0 + p[7]*x1 + p[8]*x2 + p[11];
    }
}

extern "C" void kernel_launch(void* const* d_in, const int* in_sizes, int n_in,
                              void* d_out, int out_size, void* d_ws, size_t ws_size,
                              hipStream_t stream) {
    const float* X   = (const float*)d_in[0];  // (B,V,3) fp32
    const float* Vn  = (const float*)d_in[1];  // (B,C,3) fp32
    const float* r6  = (const float*)d_in[2];  // (B,C,6) fp32
    const float* W   = (const float*)d_in[3];  // (V,C)   fp32
    const int*   idx = (const int*)d_in[4];    // (C,)    int32

    // Single dispatch; d_ws intentionally unused.
    deform_fused<<<TILES, 256, 0, stream>>>(X, Vn, r6, idx, W, (float*)d_out);
}